// Round 1
// baseline (382.135 us; speedup 1.0000x reference)
//
#include <hip/hip_runtime.h>

#define B_ROWS 65536
#define F_FEAT 39
#define V_VOC  100000
#define D_PAD  640
#define BN_EPS 1e-5f

typedef __bf16 bf16x8 __attribute__((ext_vector_type(8)));
typedef float  f32x16 __attribute__((ext_vector_type(16)));

__device__ __forceinline__ unsigned short toBF(float x) {
  unsigned int u = __float_as_uint(x);
  u += 0x7fffu + ((u >> 16) & 1u);
  return (unsigned short)(u >> 16);
}

// ---------------- K1: gather fm2, write Xt (bf16, transposed, padded), fs = FM second-order ----
__global__ __launch_bounds__(256) void k1_gather(
    const int* __restrict__ Xi, const float* __restrict__ Xv,
    const float* __restrict__ emb2, unsigned short* __restrict__ XT,
    float* __restrict__ fs) {
  const int b0 = blockIdx.x * 32;
  __shared__ int            sIdx[32][40];
  __shared__ float          sXv[32][40];
  __shared__ unsigned short xt[32][648];   // padded stride: banks

  for (int u = threadIdx.x; u < 32 * 39; u += 256) {
    int r = u / 39, f = u - r * 39;
    sIdx[r][f] = Xi[(size_t)(b0 + r) * 39 + f];
    sXv[r][f]  = Xv[(size_t)(b0 + r) * 39 + f];
  }
  __syncthreads();

  const int r = threadIdx.x >> 3, ec = threadIdx.x & 7;  // ec = e-pair index (2 floats)
  float sv0 = 0.f, sv1 = 0.f, ss0 = 0.f, ss1 = 0.f;
#pragma unroll 4
  for (int f = 0; f < 39; ++f) {
    int id = sIdx[r][f];
    float xv = sXv[r][f];
    const float2 v = *reinterpret_cast<const float2*>(
        emb2 + ((size_t)f * V_VOC + id) * 16 + ec * 2);
    float a = v.x * xv, b = v.y * xv;
    sv0 += a; ss0 += a * a;
    sv1 += b; ss1 += b * b;
    unsigned int pk = (unsigned int)toBF(a) | ((unsigned int)toBF(b) << 16);
    *reinterpret_cast<unsigned int*>(&xt[r][f * 16 + ec * 2]) = pk;
  }
  float p = (sv0 * sv0 - ss0) + (sv1 * sv1 - ss1);
  p += __shfl_xor(p, 1);
  p += __shfl_xor(p, 2);
  p += __shfl_xor(p, 4);
  if (ec == 0) fs[b0 + r] = 0.5f * p;
  __syncthreads();

  // write Xt[m][b0..b0+31]; m=624 -> ones column, 625..639 -> zeros
  for (int m = threadIdx.x; m < 640; m += 256) {
    unsigned short* dst = XT + (size_t)m * B_ROWS + b0;
    unsigned int q[16];
    if (m < 624) {
#pragma unroll
      for (int rr = 0; rr < 16; ++rr)
        q[rr] = (unsigned int)xt[2 * rr][m] | ((unsigned int)xt[2 * rr + 1][m] << 16);
    } else {
      unsigned int fill = (m == 624) ? 0x3f803f80u : 0u;
#pragma unroll
      for (int rr = 0; rr < 16; ++rr) q[rr] = fill;
    }
#pragma unroll
    for (int c = 0; c < 4; ++c) {
      uint4 w;
      w.x = q[c * 4]; w.y = q[c * 4 + 1]; w.z = q[c * 4 + 2]; w.w = q[c * 4 + 3];
      *reinterpret_cast<uint4*>(dst + c * 8) = w;
    }
  }
}

// ---------------- K2: M += Xt * Xt^T  (640x640, symmetric tiles ti<=tj), bf16 MFMA ----------
#define KSPLIT 32
__global__ __launch_bounds__(256) void k2_syrk(const unsigned short* __restrict__ XT,
                                               float* __restrict__ M) {
  const int ks = blockIdx.x & (KSPLIT - 1);
  int pair = blockIdx.x >> 5;
  int ti = 0, p = pair;
  while (p >= 5 - ti) { p -= 5 - ti; ++ti; }
  const int tj = ti + p;

  __shared__ unsigned short pa[128 * 64];
  __shared__ unsigned short pb[128 * 64];

  const int lane = threadIdx.x & 63, wid = threadIdx.x >> 6;
  const int wm = wid >> 1, wn = wid & 1;
  const int rl = lane & 31, hh = lane >> 5;

  f32x16 acc00, acc01, acc10, acc11;
#pragma unroll
  for (int i = 0; i < 16; ++i) { acc00[i] = 0.f; acc01[i] = 0.f; acc10[i] = 0.f; acc11[i] = 0.f; }

  const int krange = B_ROWS / KSPLIT;  // 2048
  const int kbase = ks * krange;

  for (int kt = 0; kt < krange; kt += 64) {
    const int k0 = kbase + kt;
#pragma unroll
    for (int g2 = 0; g2 < 4; ++g2) {
      const int g = threadIdx.x + g2 * 256;
      const int r = g >> 3, j = g & 7;
      uint4 va = *reinterpret_cast<const uint4*>(XT + (size_t)(ti * 128 + r) * B_ROWS + k0 + j * 8);
      *reinterpret_cast<uint4*>((char*)pa + r * 128 + ((j ^ (r & 7)) << 4)) = va;
      uint4 vb = *reinterpret_cast<const uint4*>(XT + (size_t)(tj * 128 + r) * B_ROWS + k0 + j * 8);
      *reinterpret_cast<uint4*>((char*)pb + r * 128 + ((j ^ (r & 7)) << 4)) = vb;
    }
    __syncthreads();
#pragma unroll
    for (int kc = 0; kc < 4; ++kc) {
      const int ra0 = wm * 64 + rl, ra1 = wm * 64 + 32 + rl;
      const int rb0 = wn * 64 + rl, rb1 = wn * 64 + 32 + rl;
      bf16x8 a0 = *reinterpret_cast<const bf16x8*>((char*)pa + ra0 * 128 + (((kc * 2 + hh) ^ (ra0 & 7)) << 4));
      bf16x8 a1 = *reinterpret_cast<const bf16x8*>((char*)pa + ra1 * 128 + (((kc * 2 + hh) ^ (ra1 & 7)) << 4));
      bf16x8 b0 = *reinterpret_cast<const bf16x8*>((char*)pb + rb0 * 128 + (((kc * 2 + hh) ^ (rb0 & 7)) << 4));
      bf16x8 b1 = *reinterpret_cast<const bf16x8*>((char*)pb + rb1 * 128 + (((kc * 2 + hh) ^ (rb1 & 7)) << 4));
      acc00 = __builtin_amdgcn_mfma_f32_32x32x16_bf16(a0, b0, acc00, 0, 0, 0);
      acc01 = __builtin_amdgcn_mfma_f32_32x32x16_bf16(a0, b1, acc01, 0, 0, 0);
      acc10 = __builtin_amdgcn_mfma_f32_32x32x16_bf16(a1, b0, acc10, 0, 0, 0);
      acc11 = __builtin_amdgcn_mfma_f32_32x32x16_bf16(a1, b1, acc11, 0, 0, 0);
    }
    __syncthreads();
  }

#pragma unroll
  for (int rr = 0; rr < 16; ++rr) {
    const int rloc = (rr & 3) + ((rr >> 2) << 3) + hh * 4;
    const int row0 = ti * 128 + wm * 64 + rloc;
    const int row1 = row0 + 32;
    const int col0 = tj * 128 + wn * 64 + rl;
    atomicAdd(&M[row0 * D_PAD + col0], acc00[rr]);
    atomicAdd(&M[row0 * D_PAD + col0 + 32], acc01[rr]);
    atomicAdd(&M[row1 * D_PAD + col0], acc10[rr]);
    atomicAdd(&M[row1 * D_PAD + col0 + 32], acc11[rr]);
  }
}

// ---------------- K3a: Cov + mu from M --------------------------------------------------------
__device__ __forceinline__ float fetchM(const float* M, int a, int b) {
  if ((a >> 7) > (b >> 7)) { int t = a; a = b; b = t; }
  return M[a * D_PAD + b];
}
__global__ void k3a_cov(const float* __restrict__ M, float* __restrict__ Cov,
                        float* __restrict__ mu) {
  const int i = blockIdx.x;
  const float inv = 1.f / 65536.f;
  const float mui = fetchM(M, 624, i) * inv;
  for (int j = threadIdx.x; j < D_PAD; j += 256) {
    float muj = fetchM(M, 624, j) * inv;
    Cov[i * D_PAD + j] = fetchM(M, i, j) * inv - mui * muj;
    if (i == 0) mu[j] = muj;
  }
}

// ---------------- qform: alpha[k] = g[k] * rsqrt( W[:,k]^T Cov W[:,k] + eps ), 2 k's/block -----
__global__ __launch_bounds__(256) void qform(const float* __restrict__ Cov,
                                             const float* __restrict__ W, const int ldw,
                                             const float* __restrict__ g,
                                             float* __restrict__ alpha) {
  const int k0 = blockIdx.x * 2;
  __shared__ float w0s[624], w1s[624];
  for (int i = threadIdx.x; i < 624; i += 256) {
    w0s[i] = W[(size_t)i * ldw + k0];
    w1s[i] = W[(size_t)i * ldw + k0 + 1];
  }
  __syncthreads();
  const int j0 = threadIdx.x, j1 = threadIdx.x + 256, j2 = threadIdx.x + 512;
  const bool v2 = (j2 < 624);
  const float wj00 = w0s[j0], wj01 = w0s[j1], wj02 = v2 ? w0s[j2] : 0.f;
  const float wj10 = w1s[j0], wj11 = w1s[j1], wj12 = v2 ? w1s[j2] : 0.f;
  float acc0 = 0.f, acc1 = 0.f;
  for (int i = 0; i < 624; ++i) {
    const float wi0 = w0s[i], wi1 = w1s[i];
    const float* row = Cov + i * D_PAD;
    const float c0 = row[j0], c1 = row[j1], c2 = v2 ? row[j2] : 0.f;
    acc0 += wi0 * (c0 * wj00 + c1 * wj01 + c2 * wj02);
    acc1 += wi1 * (c0 * wj10 + c1 * wj11 + c2 * wj12);
  }
#pragma unroll
  for (int off = 32; off > 0; off >>= 1) {
    acc0 += __shfl_down(acc0, off);
    acc1 += __shfl_down(acc1, off);
  }
  __shared__ float pr[2][4];
  const int lane = threadIdx.x & 63, wv = threadIdx.x >> 6;
  if (lane == 0) { pr[0][wv] = acc0; pr[1][wv] = acc1; }
  __syncthreads();
  if (threadIdx.x == 0) {
    float v0 = pr[0][0] + pr[0][1] + pr[0][2] + pr[0][3];
    float v1 = pr[1][0] + pr[1][1] + pr[1][2] + pr[1][3];
    alpha[k0]     = g[k0]     * rsqrtf(v0 + BN_EPS);
    alpha[k0 + 1] = g[k0 + 1] * rsqrtf(v1 + BN_EPS);
  }
}

// ---------------- K3c: G[i][j] = sum_k W1[i][k]*alpha1[k]*W2[k][j] ----------------------------
__global__ __launch_bounds__(256) void k3c_G(const float* __restrict__ W1,
                                             const float* __restrict__ alpha1,
                                             const float* __restrict__ W2,
                                             float* __restrict__ G) {
  const int i = blockIdx.x;
  __shared__ float a[512];
  for (int k = threadIdx.x; k < 512; k += 256)
    a[k] = W1[(size_t)i * 512 + k] * alpha1[k];
  __syncthreads();
  const int j = threadIdx.x;
  float acc = 0.f;
#pragma unroll 8
  for (int k = 0; k < 512; ++k) acc += a[k] * W2[(size_t)k * 256 + j];
  G[(size_t)i * 256 + j] = acc;
}

// ---------------- K3e: gw[i] = sum_j G[i][j]*alpha2[j];  consts = bias + sum(be2) - mu.gw -----
__global__ __launch_bounds__(256) void k3e_final(const float* __restrict__ G,
                                                 const float* __restrict__ alpha2,
                                                 const float* __restrict__ mu,
                                                 const float* __restrict__ be2,
                                                 const float* __restrict__ bias,
                                                 float* __restrict__ gw,
                                                 float* __restrict__ consts) {
  __shared__ float a2[256];
  __shared__ float gws[640];
  a2[threadIdx.x] = alpha2[threadIdx.x];
  __syncthreads();
  for (int i = threadIdx.x; i < 640; i += 256) {
    float acc = 0.f;
    if (i < 624) {
      const float* gr = G + (size_t)i * 256;
#pragma unroll 8
      for (int j = 0; j < 256; ++j) acc += gr[j] * a2[j];
    }
    gw[i] = acc;
    gws[i] = acc;
  }
  __syncthreads();
  float pm = 0.f;
  for (int i = threadIdx.x; i < 624; i += 256) pm += mu[i] * gws[i];
  float val = be2[threadIdx.x] - pm;
#pragma unroll
  for (int off = 32; off > 0; off >>= 1) val += __shfl_down(val, off);
  __shared__ float pr[4];
  const int lane = threadIdx.x & 63, wv = threadIdx.x >> 6;
  if (lane == 0) pr[wv] = val;
  __syncthreads();
  if (threadIdx.x == 0) consts[0] = bias[0] + pr[0] + pr[1] + pr[2] + pr[3];
}

// ---------------- K4: t'[f][v] = emb1[f][v] + emb2[f][v][:] . gw[f*16:...] -------------------
__global__ __launch_bounds__(256) void k4_table(const float* __restrict__ emb1,
                                                const float* __restrict__ emb2,
                                                const float* __restrict__ gw,
                                                float* __restrict__ tp) {
  const int f = blockIdx.y;
  const int v = blockIdx.x * 256 + threadIdx.x;
  __shared__ float gf[16];
  if (threadIdx.x < 16) gf[threadIdx.x] = gw[f * 16 + threadIdx.x];
  __syncthreads();
  if (v >= V_VOC) return;
  const float* e = emb2 + ((size_t)f * V_VOC + v) * 16;
  float4 x0 = *reinterpret_cast<const float4*>(e);
  float4 x1 = *reinterpret_cast<const float4*>(e + 4);
  float4 x2 = *reinterpret_cast<const float4*>(e + 8);
  float4 x3 = *reinterpret_cast<const float4*>(e + 12);
  float d = x0.x * gf[0] + x0.y * gf[1] + x0.z * gf[2] + x0.w * gf[3]
          + x1.x * gf[4] + x1.y * gf[5] + x1.z * gf[6] + x1.w * gf[7]
          + x2.x * gf[8] + x2.y * gf[9] + x2.z * gf[10] + x2.w * gf[11]
          + x3.x * gf[12] + x3.y * gf[13] + x3.z * gf[14] + x3.w * gf[15];
  tp[(size_t)f * V_VOC + v] = emb1[(size_t)f * V_VOC + v] + d;
}

// ---------------- K5: out[b] = consts + fs[b] + sum_f Xv[b][f] * t'[f][idx] ------------------
__global__ __launch_bounds__(256) void k5_out(const int* __restrict__ Xi,
                                              const float* __restrict__ Xv,
                                              const float* __restrict__ tp,
                                              const float* __restrict__ fs,
                                              const float* __restrict__ consts,
                                              float* __restrict__ out) {
  const int b0 = blockIdx.x * 128;
  __shared__ int   si[128 * 39];
  __shared__ float sx[128 * 39];
  for (int u = threadIdx.x; u < 128 * 39; u += 256) {
    si[u] = Xi[(size_t)b0 * 39 + u];
    sx[u] = Xv[(size_t)b0 * 39 + u];
  }
  __syncthreads();
  const int r = threadIdx.x >> 1, hf = threadIdx.x & 1;
  const int fb = hf ? 20 : 0, fe = hf ? 39 : 20;
  float acc = 0.f;
  for (int f = fb; f < fe; ++f) {
    int id = si[r * 39 + f];
    acc += sx[r * 39 + f] * tp[f * V_VOC + id];
  }
  acc += __shfl_xor(acc, 1);
  if (hf == 0) out[b0 + r] = acc + fs[b0 + r] + consts[0];
}

// ---------------- host launch ----------------------------------------------------------------
extern "C" void kernel_launch(void* const* d_in, const int* in_sizes, int n_in,
                              void* d_out, int out_size, void* d_ws, size_t ws_size,
                              hipStream_t stream) {
  const int*   Xi   = (const int*)d_in[0];
  const float* Xv   = (const float*)d_in[1];
  const float* emb1 = (const float*)d_in[2];
  const float* emb2 = (const float*)d_in[3];
  const float* W1   = (const float*)d_in[4];
  const float* g1   = (const float*)d_in[6];
  const float* W2   = (const float*)d_in[8];
  const float* g2   = (const float*)d_in[10];
  const float* be2  = (const float*)d_in[11];
  const float* bias = (const float*)d_in[12];
  float* out = (float*)d_out;
  char* ws = (char*)d_ws;

  const size_t OFF_XT  = 0;
  const size_t OFF_M   = OFF_XT + (size_t)640 * 65536 * 2;  // 83,886,080
  const size_t OFF_COV = OFF_M + (size_t)640 * 640 * 4;
  const size_t OFF_MU  = OFF_COV + (size_t)640 * 640 * 4;
  const size_t OFF_A1  = OFF_MU + 640 * 4;
  const size_t OFF_A2  = OFF_A1 + 512 * 4;
  const size_t OFF_G   = OFF_A2 + 256 * 4;
  const size_t OFF_GW  = OFF_G + (size_t)624 * 256 * 4;
  const size_t OFF_CN  = OFF_GW + 640 * 4;
  const size_t OFF_FS  = OFF_CN + 256;
  const size_t OFF_TP  = OFF_FS + (size_t)65536 * 4;
  // total = OFF_TP + 39*100000*4 ~= 103.7 MB

  unsigned short* XT = (unsigned short*)(ws + OFF_XT);
  float* M   = (float*)(ws + OFF_M);
  float* COV = (float*)(ws + OFF_COV);
  float* MU  = (float*)(ws + OFF_MU);
  float* A1  = (float*)(ws + OFF_A1);
  float* A2  = (float*)(ws + OFF_A2);
  float* G   = (float*)(ws + OFF_G);
  float* GW  = (float*)(ws + OFF_GW);
  float* CN  = (float*)(ws + OFF_CN);
  float* FS  = (float*)(ws + OFF_FS);
  float* TP  = (float*)(ws + OFF_TP);

  hipMemsetAsync(M, 0, (size_t)640 * 640 * 4, stream);
  k1_gather<<<2048, 256, 0, stream>>>(Xi, Xv, emb2, XT, FS);
  k2_syrk<<<15 * KSPLIT, 256, 0, stream>>>(XT, M);
  k3a_cov<<<640, 256, 0, stream>>>(M, COV, MU);
  qform<<<256, 256, 0, stream>>>(COV, W1, 512, g1, A1);
  k3c_G<<<624, 256, 0, stream>>>(W1, A1, W2, G);
  qform<<<128, 256, 0, stream>>>(COV, G, 256, g2, A2);
  k3e_final<<<1, 256, 0, stream>>>(G, A2, MU, be2, bias, GW, CN);
  k4_table<<<dim3(391, 39), 256, 0, stream>>>(emb1, emb2, GW, TP);
  k5_out<<<512, 256, 0, stream>>>(Xi, Xv, TP, FS, CN, out);
}

// Round 2
// 377.112 us; speedup vs baseline: 1.0133x; 1.0133x over previous
//
#include <hip/hip_runtime.h>

#define B_ROWS 65536
#define F_FEAT 39
#define V_VOC  100000
#define D_PAD  640
#define BN_EPS 1e-5f

typedef __bf16 bf16x8 __attribute__((ext_vector_type(8)));
typedef float  f32x16 __attribute__((ext_vector_type(16)));

__device__ __forceinline__ unsigned short toBF(float x) {
  unsigned int u = __float_as_uint(x);
  u += 0x7fffu + ((u >> 16) & 1u);
  return (unsigned short)(u >> 16);
}

// ---------------- K1: gather fm2, write Xt (bf16, transposed, padded), fs = FM second-order ----
// Also zeroes M (640x640 floats, 200 per block x 2048 blocks) to avoid the
// pathologically slow rocclr fillBuffer (146 us at 11 GB/s for 1.6 MB).
__global__ __launch_bounds__(256) void k1_gather(
    const int* __restrict__ Xi, const float* __restrict__ Xv,
    const float* __restrict__ emb2, unsigned short* __restrict__ XT,
    float* __restrict__ fs, float* __restrict__ Mz) {
  // zero M: 2048 blocks * 200 floats = 640*640
  if (threadIdx.x < 200)
    Mz[(size_t)blockIdx.x * 200 + threadIdx.x] = 0.f;

  const int b0 = blockIdx.x * 32;
  __shared__ int            sIdx[32][40];
  __shared__ float          sXv[32][40];
  __shared__ unsigned short xt[32][648];   // padded stride: banks

  for (int u = threadIdx.x; u < 32 * 39; u += 256) {
    int r = u / 39, f = u - r * 39;
    sIdx[r][f] = Xi[(size_t)(b0 + r) * 39 + f];
    sXv[r][f]  = Xv[(size_t)(b0 + r) * 39 + f];
  }
  __syncthreads();

  const int r = threadIdx.x >> 3, ec = threadIdx.x & 7;  // ec = e-pair index (2 floats)
  float sv0 = 0.f, sv1 = 0.f, ss0 = 0.f, ss1 = 0.f;
#pragma unroll 4
  for (int f = 0; f < 39; ++f) {
    int id = sIdx[r][f];
    float xv = sXv[r][f];
    const float2 v = *reinterpret_cast<const float2*>(
        emb2 + ((size_t)f * V_VOC + id) * 16 + ec * 2);
    float a = v.x * xv, b = v.y * xv;
    sv0 += a; ss0 += a * a;
    sv1 += b; ss1 += b * b;
    unsigned int pk = (unsigned int)toBF(a) | ((unsigned int)toBF(b) << 16);
    *reinterpret_cast<unsigned int*>(&xt[r][f * 16 + ec * 2]) = pk;
  }
  float p = (sv0 * sv0 - ss0) + (sv1 * sv1 - ss1);
  p += __shfl_xor(p, 1);
  p += __shfl_xor(p, 2);
  p += __shfl_xor(p, 4);
  if (ec == 0) fs[b0 + r] = 0.5f * p;
  __syncthreads();

  // write Xt[m][b0..b0+31]; m=624 -> ones column, 625..639 -> zeros
  for (int m = threadIdx.x; m < 640; m += 256) {
    unsigned short* dst = XT + (size_t)m * B_ROWS + b0;
    unsigned int q[16];
    if (m < 624) {
#pragma unroll
      for (int rr = 0; rr < 16; ++rr)
        q[rr] = (unsigned int)xt[2 * rr][m] | ((unsigned int)xt[2 * rr + 1][m] << 16);
    } else {
      unsigned int fill = (m == 624) ? 0x3f803f80u : 0u;
#pragma unroll
      for (int rr = 0; rr < 16; ++rr) q[rr] = fill;
    }
#pragma unroll
    for (int c = 0; c < 4; ++c) {
      uint4 w;
      w.x = q[c * 4]; w.y = q[c * 4 + 1]; w.z = q[c * 4 + 2]; w.w = q[c * 4 + 3];
      *reinterpret_cast<uint4*>(dst + c * 8) = w;
    }
  }
}

// ---------------- K2: M += Xt * Xt^T  (640x640, symmetric tiles ti<=tj), bf16 MFMA ----------
#define KSPLIT 32
__global__ __launch_bounds__(256) void k2_syrk(const unsigned short* __restrict__ XT,
                                               float* __restrict__ M) {
  const int ks = blockIdx.x & (KSPLIT - 1);
  int pair = blockIdx.x >> 5;
  int ti = 0, p = pair;
  while (p >= 5 - ti) { p -= 5 - ti; ++ti; }
  const int tj = ti + p;

  __shared__ unsigned short pa[128 * 64];
  __shared__ unsigned short pb[128 * 64];

  const int lane = threadIdx.x & 63, wid = threadIdx.x >> 6;
  const int wm = wid >> 1, wn = wid & 1;
  const int rl = lane & 31, hh = lane >> 5;

  f32x16 acc00, acc01, acc10, acc11;
#pragma unroll
  for (int i = 0; i < 16; ++i) { acc00[i] = 0.f; acc01[i] = 0.f; acc10[i] = 0.f; acc11[i] = 0.f; }

  const int krange = B_ROWS / KSPLIT;  // 2048
  const int kbase = ks * krange;

  for (int kt = 0; kt < krange; kt += 64) {
    const int k0 = kbase + kt;
#pragma unroll
    for (int g2 = 0; g2 < 4; ++g2) {
      const int g = threadIdx.x + g2 * 256;
      const int r = g >> 3, j = g & 7;
      uint4 va = *reinterpret_cast<const uint4*>(XT + (size_t)(ti * 128 + r) * B_ROWS + k0 + j * 8);
      *reinterpret_cast<uint4*>((char*)pa + r * 128 + ((j ^ (r & 7)) << 4)) = va;
      uint4 vb = *reinterpret_cast<const uint4*>(XT + (size_t)(tj * 128 + r) * B_ROWS + k0 + j * 8);
      *reinterpret_cast<uint4*>((char*)pb + r * 128 + ((j ^ (r & 7)) << 4)) = vb;
    }
    __syncthreads();
#pragma unroll
    for (int kc = 0; kc < 4; ++kc) {
      const int ra0 = wm * 64 + rl, ra1 = wm * 64 + 32 + rl;
      const int rb0 = wn * 64 + rl, rb1 = wn * 64 + 32 + rl;
      bf16x8 a0 = *reinterpret_cast<const bf16x8*>((char*)pa + ra0 * 128 + (((kc * 2 + hh) ^ (ra0 & 7)) << 4));
      bf16x8 a1 = *reinterpret_cast<const bf16x8*>((char*)pa + ra1 * 128 + (((kc * 2 + hh) ^ (ra1 & 7)) << 4));
      bf16x8 b0 = *reinterpret_cast<const bf16x8*>((char*)pb + rb0 * 128 + (((kc * 2 + hh) ^ (rb0 & 7)) << 4));
      bf16x8 b1 = *reinterpret_cast<const bf16x8*>((char*)pb + rb1 * 128 + (((kc * 2 + hh) ^ (rb1 & 7)) << 4));
      acc00 = __builtin_amdgcn_mfma_f32_32x32x16_bf16(a0, b0, acc00, 0, 0, 0);
      acc01 = __builtin_amdgcn_mfma_f32_32x32x16_bf16(a0, b1, acc01, 0, 0, 0);
      acc10 = __builtin_amdgcn_mfma_f32_32x32x16_bf16(a1, b0, acc10, 0, 0, 0);
      acc11 = __builtin_amdgcn_mfma_f32_32x32x16_bf16(a1, b1, acc11, 0, 0, 0);
    }
    __syncthreads();
  }

#pragma unroll
  for (int rr = 0; rr < 16; ++rr) {
    const int rloc = (rr & 3) + ((rr >> 2) << 3) + hh * 4;
    const int row0 = ti * 128 + wm * 64 + rloc;
    const int row1 = row0 + 32;
    const int col0 = tj * 128 + wn * 64 + rl;
    atomicAdd(&M[row0 * D_PAD + col0], acc00[rr]);
    atomicAdd(&M[row0 * D_PAD + col0 + 32], acc01[rr]);
    atomicAdd(&M[row1 * D_PAD + col0], acc10[rr]);
    atomicAdd(&M[row1 * D_PAD + col0 + 32], acc11[rr]);
  }
}

// ---------------- K3a: Cov + mu from M --------------------------------------------------------
__device__ __forceinline__ float fetchM(const float* M, int a, int b) {
  if ((a >> 7) > (b >> 7)) { int t = a; a = b; b = t; }
  return M[a * D_PAD + b];
}
__global__ void k3a_cov(const float* __restrict__ M, float* __restrict__ Cov,
                        float* __restrict__ mu) {
  const int i = blockIdx.x;
  const float inv = 1.f / 65536.f;
  const float mui = fetchM(M, 624, i) * inv;
  for (int j = threadIdx.x; j < D_PAD; j += 256) {
    float muj = fetchM(M, 624, j) * inv;
    Cov[i * D_PAD + j] = fetchM(M, i, j) * inv - mui * muj;
    if (i == 0) mu[j] = muj;
  }
}

// ---------------- qform: alpha[k] = g[k] * rsqrt( W[:,k]^T Cov W[:,k] + eps ), 2 k's/block -----
__global__ __launch_bounds__(256) void qform(const float* __restrict__ Cov,
                                             const float* __restrict__ W, const int ldw,
                                             const float* __restrict__ g,
                                             float* __restrict__ alpha) {
  const int k0 = blockIdx.x * 2;
  __shared__ float w0s[624], w1s[624];
  for (int i = threadIdx.x; i < 624; i += 256) {
    w0s[i] = W[(size_t)i * ldw + k0];
    w1s[i] = W[(size_t)i * ldw + k0 + 1];
  }
  __syncthreads();
  const int j0 = threadIdx.x, j1 = threadIdx.x + 256, j2 = threadIdx.x + 512;
  const bool v2 = (j2 < 624);
  const float wj00 = w0s[j0], wj01 = w0s[j1], wj02 = v2 ? w0s[j2] : 0.f;
  const float wj10 = w1s[j0], wj11 = w1s[j1], wj12 = v2 ? w1s[j2] : 0.f;
  float acc0 = 0.f, acc1 = 0.f;
  for (int i = 0; i < 624; ++i) {
    const float wi0 = w0s[i], wi1 = w1s[i];
    const float* row = Cov + i * D_PAD;
    const float c0 = row[j0], c1 = row[j1], c2 = v2 ? row[j2] : 0.f;
    acc0 += wi0 * (c0 * wj00 + c1 * wj01 + c2 * wj02);
    acc1 += wi1 * (c0 * wj10 + c1 * wj11 + c2 * wj12);
  }
#pragma unroll
  for (int off = 32; off > 0; off >>= 1) {
    acc0 += __shfl_down(acc0, off);
    acc1 += __shfl_down(acc1, off);
  }
  __shared__ float pr[2][4];
  const int lane = threadIdx.x & 63, wv = threadIdx.x >> 6;
  if (lane == 0) { pr[0][wv] = acc0; pr[1][wv] = acc1; }
  __syncthreads();
  if (threadIdx.x == 0) {
    float v0 = pr[0][0] + pr[0][1] + pr[0][2] + pr[0][3];
    float v1 = pr[1][0] + pr[1][1] + pr[1][2] + pr[1][3];
    alpha[k0]     = g[k0]     * rsqrtf(v0 + BN_EPS);
    alpha[k0 + 1] = g[k0 + 1] * rsqrtf(v1 + BN_EPS);
  }
}

// ---------------- K3c: G[i][j] = sum_k W1[i][k]*alpha1[k]*W2[k][j] ----------------------------
__global__ __launch_bounds__(256) void k3c_G(const float* __restrict__ W1,
                                             const float* __restrict__ alpha1,
                                             const float* __restrict__ W2,
                                             float* __restrict__ G) {
  const int i = blockIdx.x;
  __shared__ float a[512];
  for (int k = threadIdx.x; k < 512; k += 256)
    a[k] = W1[(size_t)i * 512 + k] * alpha1[k];
  __syncthreads();
  const int j = threadIdx.x;
  float acc = 0.f;
#pragma unroll 8
  for (int k = 0; k < 512; ++k) acc += a[k] * W2[(size_t)k * 256 + j];
  G[(size_t)i * 256 + j] = acc;
}

// ---------------- K3e: gw[i] = sum_j G[i][j]*alpha2[j];  consts = bias + sum(be2) - mu.gw -----
__global__ __launch_bounds__(256) void k3e_final(const float* __restrict__ G,
                                                 const float* __restrict__ alpha2,
                                                 const float* __restrict__ mu,
                                                 const float* __restrict__ be2,
                                                 const float* __restrict__ bias,
                                                 float* __restrict__ gw,
                                                 float* __restrict__ consts) {
  __shared__ float a2[256];
  __shared__ float gws[640];
  a2[threadIdx.x] = alpha2[threadIdx.x];
  __syncthreads();
  for (int i = threadIdx.x; i < 640; i += 256) {
    float acc = 0.f;
    if (i < 624) {
      const float* gr = G + (size_t)i * 256;
#pragma unroll 8
      for (int j = 0; j < 256; ++j) acc += gr[j] * a2[j];
    }
    gw[i] = acc;
    gws[i] = acc;
  }
  __syncthreads();
  float pm = 0.f;
  for (int i = threadIdx.x; i < 624; i += 256) pm += mu[i] * gws[i];
  float val = be2[threadIdx.x] - pm;
#pragma unroll
  for (int off = 32; off > 0; off >>= 1) val += __shfl_down(val, off);
  __shared__ float pr[4];
  const int lane = threadIdx.x & 63, wv = threadIdx.x >> 6;
  if (lane == 0) pr[wv] = val;
  __syncthreads();
  if (threadIdx.x == 0) consts[0] = bias[0] + pr[0] + pr[1] + pr[2] + pr[3];
}

// ---------------- K4: t'[f][v] = emb1[f][v] + emb2[f][v][:] . gw[f*16:...] -------------------
__global__ __launch_bounds__(256) void k4_table(const float* __restrict__ emb1,
                                                const float* __restrict__ emb2,
                                                const float* __restrict__ gw,
                                                float* __restrict__ tp) {
  const int f = blockIdx.y;
  const int v = blockIdx.x * 256 + threadIdx.x;
  __shared__ float gf[16];
  if (threadIdx.x < 16) gf[threadIdx.x] = gw[f * 16 + threadIdx.x];
  __syncthreads();
  if (v >= V_VOC) return;
  const float* e = emb2 + ((size_t)f * V_VOC + v) * 16;
  float4 x0 = *reinterpret_cast<const float4*>(e);
  float4 x1 = *reinterpret_cast<const float4*>(e + 4);
  float4 x2 = *reinterpret_cast<const float4*>(e + 8);
  float4 x3 = *reinterpret_cast<const float4*>(e + 12);
  float d = x0.x * gf[0] + x0.y * gf[1] + x0.z * gf[2] + x0.w * gf[3]
          + x1.x * gf[4] + x1.y * gf[5] + x1.z * gf[6] + x1.w * gf[7]
          + x2.x * gf[8] + x2.y * gf[9] + x2.z * gf[10] + x2.w * gf[11]
          + x3.x * gf[12] + x3.y * gf[13] + x3.z * gf[14] + x3.w * gf[15];
  tp[(size_t)f * V_VOC + v] = emb1[(size_t)f * V_VOC + v] + d;
}

// ---------------- K5: out[b] = consts + fs[b] + sum_f Xv[b][f] * t'[f][idx] ------------------
__global__ __launch_bounds__(256) void k5_out(const int* __restrict__ Xi,
                                              const float* __restrict__ Xv,
                                              const float* __restrict__ tp,
                                              const float* __restrict__ fs,
                                              const float* __restrict__ consts,
                                              float* __restrict__ out) {
  const int b0 = blockIdx.x * 128;
  __shared__ int   si[128 * 39];
  __shared__ float sx[128 * 39];
  for (int u = threadIdx.x; u < 128 * 39; u += 256) {
    si[u] = Xi[(size_t)b0 * 39 + u];
    sx[u] = Xv[(size_t)b0 * 39 + u];
  }
  __syncthreads();
  const int r = threadIdx.x >> 1, hf = threadIdx.x & 1;
  const int fb = hf ? 20 : 0, fe = hf ? 39 : 20;
  float acc = 0.f;
  for (int f = fb; f < fe; ++f) {
    int id = si[r * 39 + f];
    acc += sx[r * 39 + f] * tp[f * V_VOC + id];
  }
  acc += __shfl_xor(acc, 1);
  if (hf == 0) out[b0 + r] = acc + fs[b0 + r] + consts[0];
}

// ---------------- host launch ----------------------------------------------------------------
extern "C" void kernel_launch(void* const* d_in, const int* in_sizes, int n_in,
                              void* d_out, int out_size, void* d_ws, size_t ws_size,
                              hipStream_t stream) {
  const int*   Xi   = (const int*)d_in[0];
  const float* Xv   = (const float*)d_in[1];
  const float* emb1 = (const float*)d_in[2];
  const float* emb2 = (const float*)d_in[3];
  const float* W1   = (const float*)d_in[4];
  const float* g1   = (const float*)d_in[6];
  const float* W2   = (const float*)d_in[8];
  const float* g2   = (const float*)d_in[10];
  const float* be2  = (const float*)d_in[11];
  const float* bias = (const float*)d_in[12];
  float* out = (float*)d_out;
  char* ws = (char*)d_ws;

  const size_t OFF_XT  = 0;
  const size_t OFF_M   = OFF_XT + (size_t)640 * 65536 * 2;  // 83,886,080
  const size_t OFF_COV = OFF_M + (size_t)640 * 640 * 4;
  const size_t OFF_MU  = OFF_COV + (size_t)640 * 640 * 4;
  const size_t OFF_A1  = OFF_MU + 640 * 4;
  const size_t OFF_A2  = OFF_A1 + 512 * 4;
  const size_t OFF_G   = OFF_A2 + 256 * 4;
  const size_t OFF_GW  = OFF_G + (size_t)624 * 256 * 4;
  const size_t OFF_CN  = OFF_GW + 640 * 4;
  const size_t OFF_FS  = OFF_CN + 256;
  const size_t OFF_TP  = OFF_FS + (size_t)65536 * 4;
  // total = OFF_TP + 39*100000*4 ~= 103.7 MB

  unsigned short* XT = (unsigned short*)(ws + OFF_XT);
  float* M   = (float*)(ws + OFF_M);
  float* COV = (float*)(ws + OFF_COV);
  float* MU  = (float*)(ws + OFF_MU);
  float* A1  = (float*)(ws + OFF_A1);
  float* A2  = (float*)(ws + OFF_A2);
  float* G   = (float*)(ws + OFF_G);
  float* GW  = (float*)(ws + OFF_GW);
  float* CN  = (float*)(ws + OFF_CN);
  float* FS  = (float*)(ws + OFF_FS);
  float* TP  = (float*)(ws + OFF_TP);

  k1_gather<<<2048, 256, 0, stream>>>(Xi, Xv, emb2, XT, FS, M);
  k2_syrk<<<15 * KSPLIT, 256, 0, stream>>>(XT, M);
  k3a_cov<<<640, 256, 0, stream>>>(M, COV, MU);
  qform<<<256, 256, 0, stream>>>(COV, W1, 512, g1, A1);
  k3c_G<<<624, 256, 0, stream>>>(W1, A1, W2, G);
  qform<<<128, 256, 0, stream>>>(COV, G, 256, g2, A2);
  k3e_final<<<1, 256, 0, stream>>>(G, A2, MU, be2, bias, GW, CN);
  k4_table<<<dim3(391, 39), 256, 0, stream>>>(emb1, emb2, GW, TP);
  k5_out<<<512, 256, 0, stream>>>(Xi, Xv, TP, FS, CN, out);
}